// Round 3
// baseline (753.067 us; speedup 1.0000x reference)
//
#include <hip/hip_runtime.h>

// ResnetHyper: pref/chunk MLP (fp32) + huge einsum out[c,k,w] = rep[c,:] . ws[k,w,:]
// MLP exact in fp32 (tiny). Big GEMM (M=105,K=512,N=220000) via bf16 MFMA,
// memory-bound on streaming ws (450.6 MB fp32).
//
// R3 change: persistent gemm blocks. Grid = 256 (1 block/CU, LDS=114 KB caps
// occupancy at 1 anyway). Each block stages repf->LDS ONCE, then grid-strides
// over 128-col tiles. ws pipeline deepened to 4 stages with slot = s & 3;
// since 16 % 4 == 0, steps 12..15 of tile k refill with stages 0..3 of tile
// k+1 using identical static slot indices -- the HBM prefetch pipeline never
// drains across tiles. Next-tile prefetch issues BEFORE current-tile stores,
// so no waitcnt forces a store drain. A(0) prefetched at s=15 (odd -> Aa) so
// the A double-buffer also rolls across tiles. This removes the ~2 us/block
// of staging+prologue+tail overhead R2 paid 6.7x per CU.

typedef __bf16 bf16x8 __attribute__((ext_vector_type(8)));
typedef float f32x4 __attribute__((ext_vector_type(4)));

#define NUM_CHUNKS 105
#define HIDDEN 512
#define N_COLS 220000   // 11 * 20000
#define PAD_CHUNKS 112  // 7 M-tiles * 16
#define REP_CHUNKS 7168 // bf16x8 chunks = 114688 B
#define N_TILES 1719    // ceil(220000 / 128)
#define GEMM_BLOCKS 256

// ---------------- Kernel 1: MLP -> rep bf16 in MFMA A-fragment layout --------
// grid: 112 blocks x 512 threads (1 output row per thread);
// blocks 105..111 zero the padded fragment slots
__global__ void mlp_kernel(const float* __restrict__ pref,       // [2]
                           const float* __restrict__ pref_emb,   // [2][64]
                           const float* __restrict__ chunk_emb,  // [105][64]
                           const float* __restrict__ W1, const float* __restrict__ b1,
                           const float* __restrict__ W2, const float* __restrict__ b2,
                           const float* __restrict__ W3, const float* __restrict__ b3,
                           __bf16* __restrict__ repf) {
  __shared__ float x[128];
  __shared__ float h1[512];
  __shared__ float h2[512];
  const int tid = threadIdx.x;   // 0..511
  const int c = blockIdx.x;
  const int t = c >> 4, mmc = c & 15;
  const int jj = tid;
  const int ss = jj >> 5, qq = (jj >> 3) & 3, j = jj & 7;
  const long fidx = (((long)(ss * 7 + t) * 4 + qq) * 16 + mmc) * 8 + j;

  if (c >= NUM_CHUNKS) {
    repf[fidx] = (__bf16)0.f;   // padded chunks m=105..111 contribute 0
    return;
  }

  if (tid < 64) {
    x[tid] = pref[0] * pref_emb[tid] + pref[1] * pref_emb[64 + tid];
  } else if (tid < 128) {
    x[tid] = chunk_emb[c * 64 + (tid - 64)];
  }
  __syncthreads();

  // layer 1: h1 = relu(x @ W1.T + b1); 4 partial sums break the FMA dep chain
  {
    const f32x4* wr = (const f32x4*)(W1 + jj * 128);
    float p0 = 0.f, p1 = 0.f, p2 = 0.f, p3 = 0.f;
#pragma unroll
    for (int i = 0; i < 32; i += 4) {
      f32x4 wa = wr[i], wb = wr[i + 1], wc = wr[i + 2], wd = wr[i + 3];
      p0 += wa[0] * x[i * 4 + 0] + wa[1] * x[i * 4 + 1] + wa[2] * x[i * 4 + 2] + wa[3] * x[i * 4 + 3];
      p1 += wb[0] * x[i * 4 + 4] + wb[1] * x[i * 4 + 5] + wb[2] * x[i * 4 + 6] + wb[3] * x[i * 4 + 7];
      p2 += wc[0] * x[i * 4 + 8] + wc[1] * x[i * 4 + 9] + wc[2] * x[i * 4 + 10] + wc[3] * x[i * 4 + 11];
      p3 += wd[0] * x[i * 4 + 12] + wd[1] * x[i * 4 + 13] + wd[2] * x[i * 4 + 14] + wd[3] * x[i * 4 + 15];
    }
    h1[jj] = fmaxf((p0 + p1) + (p2 + p3) + b1[jj], 0.f);
  }
  __syncthreads();

  // layer 2
  {
    const f32x4* wr = (const f32x4*)(W2 + jj * 512);
    float p0 = 0.f, p1 = 0.f, p2 = 0.f, p3 = 0.f;
#pragma unroll 8
    for (int i = 0; i < 128; i += 4) {
      f32x4 wa = wr[i], wb = wr[i + 1], wc = wr[i + 2], wd = wr[i + 3];
      p0 += wa[0] * h1[i * 4 + 0] + wa[1] * h1[i * 4 + 1] + wa[2] * h1[i * 4 + 2] + wa[3] * h1[i * 4 + 3];
      p1 += wb[0] * h1[i * 4 + 4] + wb[1] * h1[i * 4 + 5] + wb[2] * h1[i * 4 + 6] + wb[3] * h1[i * 4 + 7];
      p2 += wc[0] * h1[i * 4 + 8] + wc[1] * h1[i * 4 + 9] + wc[2] * h1[i * 4 + 10] + wc[3] * h1[i * 4 + 11];
      p3 += wd[0] * h1[i * 4 + 12] + wd[1] * h1[i * 4 + 13] + wd[2] * h1[i * 4 + 14] + wd[3] * h1[i * 4 + 15];
    }
    h2[jj] = fmaxf((p0 + p1) + (p2 + p3) + b2[jj], 0.f);
  }
  __syncthreads();

  // layer 3 (no relu) + scatter into A-fragment layout
  {
    const f32x4* wr = (const f32x4*)(W3 + jj * 512);
    float p0 = 0.f, p1 = 0.f, p2 = 0.f, p3 = 0.f;
#pragma unroll 8
    for (int i = 0; i < 128; i += 4) {
      f32x4 wa = wr[i], wb = wr[i + 1], wc = wr[i + 2], wd = wr[i + 3];
      p0 += wa[0] * h2[i * 4 + 0] + wa[1] * h2[i * 4 + 1] + wa[2] * h2[i * 4 + 2] + wa[3] * h2[i * 4 + 3];
      p1 += wb[0] * h2[i * 4 + 4] + wb[1] * h2[i * 4 + 5] + wb[2] * h2[i * 4 + 6] + wb[3] * h2[i * 4 + 7];
      p2 += wc[0] * h2[i * 4 + 8] + wc[1] * h2[i * 4 + 9] + wc[2] * h2[i * 4 + 10] + wc[3] * h2[i * 4 + 11];
      p3 += wd[0] * h2[i * 4 + 12] + wd[1] * h2[i * 4 + 13] + wd[2] * h2[i * 4 + 14] + wd[3] * h2[i * 4 + 15];
    }
    repf[fidx] = (__bf16)((p0 + p1) + (p2 + p3) + b3[jj]);
  }
}

// ---------------- Kernel 2: C[105 x 220000] = rep @ ws^T via bf16 MFMA -------
// Persistent: grid 256 x 256 threads (4 waves, 32 cols/wave/tile).
// repf staged in LDS once per block; seamless depth-4 ws register pipeline
// across grid-strided 128-col tiles.
__global__ __launch_bounds__(256, 1) void gemm_ws(
    const float* __restrict__ ws,    // [220000][512]
    const bf16x8* __restrict__ repf, // fragment chunks (linear)
    float* __restrict__ out) {       // [105][220000]
  __shared__ bf16x8 Alds[REP_CHUNKS];  // 114688 B

  const int tid = threadIdx.x;
  const int lane = tid & 63;
  const int wv = tid >> 6;        // wave 0..3
  const int q = lane >> 4;
  const int mm = lane & 15;

  // ---- stage repf -> LDS, linear (dest order == source order) ----
#pragma unroll
  for (int i = 0; i < 28; ++i) {
    const bf16x8* g = repf + wv * 1792 + i * 64 + lane;
    __builtin_amdgcn_global_load_lds(
        (const __attribute__((address_space(1))) unsigned int*)g,
        (__attribute__((address_space(3))) unsigned int*)&Alds[wv * 1792 + i * 64],
        16, 0, 0);
  }

  // ---- first tile pointers ----
  long tile = blockIdx.x;
  long cb = tile * 128 + wv * 32;
  long col0 = cb + mm;
  long col1 = col0 + 16;
  bool v0 = col0 < N_COLS;
  bool v1 = col1 < N_COLS;
  const f32x4* w0 = (const f32x4*)(ws + (v0 ? col0 : 0) * 512) + q * 2;
  const f32x4* w1 = (const f32x4*)(ws + (v1 ? col1 : 0) * 512) + q * 2;

  // ---- ws prologue: 4 stages issued BEFORE the barrier (hides under the
  //      staging drain; the barrier's vmcnt(0) covers both) ----
  f32x4 X0[4], X1[4], Y0[4], Y1[4];
#pragma unroll
  for (int p = 0; p < 4; ++p) {
    X0[p] = __builtin_nontemporal_load(w0 + p * 8);
    X1[p] = __builtin_nontemporal_load(w0 + p * 8 + 1);
    Y0[p] = __builtin_nontemporal_load(w1 + p * 8);
    Y1[p] = __builtin_nontemporal_load(w1 + p * 8 + 1);
  }

  __syncthreads();  // staging + prologue complete

  // A double-buffer from LDS; Aa = A(0) once (rolls over across tiles)
  bf16x8 Aa[7], Ab[7];
#pragma unroll
  for (int t = 0; t < 7; ++t) Aa[t] = Alds[t * 64 + lane];

  for (;;) {
    f32x4 acc0[7], acc1[7];
#pragma unroll
    for (int t = 0; t < 7; ++t) {
      acc0[t] = (f32x4){0.f, 0.f, 0.f, 0.f};
      acc1[t] = (f32x4){0.f, 0.f, 0.f, 0.f};
    }

    // next-tile pointers (for the cross-tile refills at s=12..15)
    const long ntile = tile + GEMM_BLOCKS;
    const bool have_next = ntile < N_TILES;
    long ncb = ntile * 128 + wv * 32;
    long ncol0 = ncb + mm;
    long ncol1 = ncol0 + 16;
    bool nv0 = ncol0 < N_COLS;
    bool nv1 = ncol1 < N_COLS;
    const f32x4* nw0 = (const f32x4*)(ws + ((have_next && nv0) ? ncol0 : 0) * 512) + q * 2;
    const f32x4* nw1 = (const f32x4*)(ws + ((have_next && nv1) ? ncol1 : 0) * 512) + q * 2;

#pragma unroll
    for (int s = 0; s < 16; ++s) {
      const int slot = s & 3;  // static; 16%4==0 -> same mapping every tile
      // (1) convert ws stage s (waits only on its own 4 loads)
      f32x4 x0 = X0[slot], x1 = X1[slot], y0 = Y0[slot], y1 = Y1[slot];
      bf16x8 b0, b1;
#pragma unroll
      for (int jv = 0; jv < 4; ++jv) {
        b0[jv] = (__bf16)x0[jv];
        b0[4 + jv] = (__bf16)x1[jv];
        b1[jv] = (__bf16)y0[jv];
        b1[4 + jv] = (__bf16)y1[jv];
      }
      // (2) MFMA with current A buffer
#pragma unroll
      for (int t = 0; t < 7; ++t) {
        bf16x8 a = (s & 1) ? Ab[t] : Aa[t];
        acc0[t] = __builtin_amdgcn_mfma_f32_16x16x32_bf16(a, b0, acc0[t], 0, 0, 0);
        acc1[t] = __builtin_amdgcn_mfma_f32_16x16x32_bf16(a, b1, acc1[t], 0, 0, 0);
      }
      // (3) prefetch A((s+1)&15) from LDS into the other buffer
      //     (s=15 -> A(0) into Aa: rolls over for the next tile)
      {
        const int sn = (s + 1) & 15;
#pragma unroll
        for (int t = 0; t < 7; ++t) {
          if (s & 1) Aa[t] = Alds[sn * 448 + t * 64 + lane];
          else       Ab[t] = Alds[sn * 448 + t * 64 + lane];
        }
      }
      // (4) refill consumed slot: same tile s+4, or next tile stage s-12
      if (s < 12) {
        X0[slot] = __builtin_nontemporal_load(w0 + (s + 4) * 8);
        X1[slot] = __builtin_nontemporal_load(w0 + (s + 4) * 8 + 1);
        Y0[slot] = __builtin_nontemporal_load(w1 + (s + 4) * 8);
        Y1[slot] = __builtin_nontemporal_load(w1 + (s + 4) * 8 + 1);
      } else if (have_next) {
        X0[slot] = __builtin_nontemporal_load(nw0 + (s - 12) * 8);
        X1[slot] = __builtin_nontemporal_load(nw0 + (s - 12) * 8 + 1);
        Y0[slot] = __builtin_nontemporal_load(nw1 + (s - 12) * 8);
        Y1[slot] = __builtin_nontemporal_load(nw1 + (s - 12) * 8 + 1);
      }
    }

    // stores for this tile (after next-tile prefetch: no store-drain stall)
    // C/D layout: col = lane&15, row = (lane>>4)*4 + reg (per M-tile t: +t*16)
#pragma unroll
    for (int t = 0; t < 7; ++t) {
      const int mbase = t * 16 + q * 4;
#pragma unroll
      for (int r = 0; r < 4; ++r) {
        const int m = mbase + r;
        if (m < NUM_CHUNKS) {
          if (v0) __builtin_nontemporal_store(acc0[t][r], out + (long)m * N_COLS + col0);
          if (v1) __builtin_nontemporal_store(acc1[t][r], out + (long)m * N_COLS + col1);
        }
      }
    }

    if (!have_next) break;
    tile = ntile;
    col0 = ncol0; col1 = ncol1; v0 = nv0; v1 = nv1; w0 = nw0; w1 = nw1;
  }
}

extern "C" void kernel_launch(void* const* d_in, const int* in_sizes, int n_in,
                              void* d_out, int out_size, void* d_ws, size_t ws_size,
                              hipStream_t stream) {
  const float* pref      = (const float*)d_in[0];
  const float* pref_emb  = (const float*)d_in[1];
  const float* chunk_emb = (const float*)d_in[2];
  const float* W1 = (const float*)d_in[3];
  const float* b1 = (const float*)d_in[4];
  const float* W2 = (const float*)d_in[5];
  const float* b2 = (const float*)d_in[6];
  const float* W3 = (const float*)d_in[7];
  const float* b3 = (const float*)d_in[8];
  const float* ws = (const float*)d_in[9];
  float* out = (float*)d_out;
  __bf16* repf = (__bf16*)d_ws;

  // pad blocks (c=105..111) zero their fragment slots; no memset needed
  mlp_kernel<<<PAD_CHUNKS, 512, 0, stream>>>(pref, pref_emb, chunk_emb,
                                             W1, b1, W2, b2, W3, b3, repf);
  gemm_ws<<<GEMM_BLOCKS, 256, 0, stream>>>(ws, (const bf16x8*)d_ws, out);
}